// Round 1
// baseline (91.940 us; speedup 1.0000x reference)
//
#include <hip/hip_runtime.h>
#include <hip/hip_bf16.h>
#include <stdint.h>

#define B_N 8192
#define D_N 1024
#define K_N 8
#define H_N 2048

#define BM 352
#define BN 256
#define GRID_MT 32
// LDS map (bytes): 4 K-tile buffers (BK=32) of (A 22528 + B 16384) = 38912:
//   buf0=0 buf1=38912 buf2=77824 buf3=116736 (end 155648)
//   ro=155648(1408) pll=157056(5632)  total 162688 (<=163840)
#define ABUF 22528
#define BUFSZ 38912
#define RO_OFF 155648
#define PLL_OFF 157056
#define GEMM_LDS 162688

typedef unsigned int u32;
typedef unsigned short u16;
typedef __attribute__((ext_vector_type(8))) short short8;
typedef __attribute__((ext_vector_type(4))) float float4v;

struct __align__(8) us4 { u16 x, y, z, w; };

__device__ __forceinline__ u16 f2bf(float f) {
    union { float f; u32 u; } v; v.f = f;
    u32 u = v.u;
    u32 r = (u + 0x7fffu + ((u >> 16) & 1u)) >> 16;
    return (u16)r;
}

__device__ __forceinline__ float fast_tanh(float x) {
    float t = __expf(2.0f * x);
    return 1.0f - 2.0f * __builtin_amdgcn_rcpf(t + 1.0f);
}

__device__ __forceinline__ void async_copy16(void* lds, const void* g) {
    __builtin_amdgcn_global_load_lds(
        (const __attribute__((address_space(1))) void*)g,
        (__attribute__((address_space(3))) void*)lds, 16, 0, 0);
}

// ---------------- routing: f64 argmin + x->bf16 (NO atomics) ----------------
__global__ void route_kernel(const float* __restrict__ x,
                             const float* __restrict__ cent,
                             u16* __restrict__ xbf,
                             int* __restrict__ cluster,
                             u32* __restrict__ counts) {
    int tid = threadIdx.x;
    if (blockIdx.x == 0 && tid < K_N) counts[tid * 32] = 0;  // zero strided counters
    int wave = tid >> 6, lane = tid & 63;
    int b = blockIdx.x * 4 + wave;
    const float* xr = x + (size_t)b * D_N;

    float4 xv[4];
#pragma unroll
    for (int i = 0; i < 4; ++i)
        xv[i] = *(const float4*)(xr + i * 256 + lane * 4);

#pragma unroll
    for (int i = 0; i < 4; ++i) {
        us4 o;
        o.x = f2bf(xv[i].x); o.y = f2bf(xv[i].y);
        o.z = f2bf(xv[i].z); o.w = f2bf(xv[i].w);
        *(us4*)(xbf + (size_t)b * D_N + i * 256 + lane * 4) = o;
    }

    double acc[K_N];
#pragma unroll
    for (int k = 0; k < K_N; ++k) {
        const float* cr = cent + k * D_N;
        double s = 0.0;
#pragma unroll
        for (int i = 0; i < 4; ++i) {
            float4 cv = *(const float4*)(cr + i * 256 + lane * 4);
            double d0 = (double)xv[i].x - (double)cv.x; s += d0 * d0;
            double d1 = (double)xv[i].y - (double)cv.y; s += d1 * d1;
            double d2 = (double)xv[i].z - (double)cv.z; s += d2 * d2;
            double d3 = (double)xv[i].w - (double)cv.w; s += d3 * d3;
        }
        acc[k] = s;
    }
#pragma unroll
    for (int k = 0; k < K_N; ++k) {
        double v = acc[k];
        for (int off = 32; off; off >>= 1) v += __shfl_down(v, off);
        acc[k] = v;
    }
    if (lane == 0) {
        int best = 0; double bv = acc[0];
#pragma unroll
        for (int k = 1; k < K_N; ++k)
            if (acc[k] < bv) { bv = acc[k]; best = k; }
        cluster[b] = best;
    }
}

// ---------------- parallel binning: 32 blocks, ballot-rank + block reserve ----------------
__global__ void scatter_kernel(const int* __restrict__ cluster,
                               u32* __restrict__ counts,
                               u32* __restrict__ idxl) {
    __shared__ u32 wcnt[4][K_N];
    __shared__ u32 gb[K_N];
    int tid = threadIdx.x;
    int b = blockIdx.x * 256 + tid;
    int lane = tid & 63, wid = tid >> 6;
    int cl = cluster[b];
    unsigned long long lower = (1ull << lane) - 1ull;
    u32 rank = 0;
#pragma unroll
    for (int k = 0; k < K_N; ++k) {
        unsigned long long mk = __ballot(cl == k);
        if (k == cl) rank = (u32)__popcll(mk & lower);
        if (lane == 0) wcnt[wid][k] = (u32)__popcll(mk);
    }
    __syncthreads();
    if (tid < K_N) {
        u32 tot = wcnt[0][tid] + wcnt[1][tid] + wcnt[2][tid] + wcnt[3][tid];
        gb[tid] = atomicAdd(&counts[tid * 32], tot);   // reserve range (order-free)
    }
    __syncthreads();
    u32 woff = 0;
    if (wid > 0) woff += wcnt[0][cl];
    if (wid > 1) woff += wcnt[1][cl];
    if (wid > 2) woff += wcnt[2][cl];
    idxl[(size_t)cl * B_N + gb[cl] + woff + rank] = (u32)b;
}

// ---------------- W1[k,d,h] f32 -> W1t[k,h,d] bf16 (vectorized) ----------------
__global__ void w1t_kernel(const float* __restrict__ w1, u16* __restrict__ w1t) {
    __shared__ float ts[64][65];
    int tid = threadIdx.x;
    int h0 = blockIdx.x * 64, d0 = blockIdx.y * 64, k = blockIdx.z;
    const float* src = w1 + ((size_t)k * D_N + d0) * H_N + h0;
#pragma unroll
    for (int i = 0; i < 4; ++i) {
        int q = i * 256 + tid;
        int r = q >> 4, c4 = (q & 15) * 4;          // d-row, h-col4
        float4 v = *(const float4*)(src + (size_t)r * H_N + c4);
        ts[c4 + 0][r] = v.x; ts[c4 + 1][r] = v.y;
        ts[c4 + 2][r] = v.z; ts[c4 + 3][r] = v.w;
    }
    __syncthreads();
    u16* dst = w1t + ((size_t)k * H_N + h0) * D_N + d0;
#pragma unroll
    for (int i = 0; i < 4; ++i) {
        int q = i * 256 + tid;
        int hr = q >> 4, d4 = (q & 15) * 4;         // h-row, d-col4
        us4 o;
        o.x = f2bf(ts[hr][d4 + 0]); o.y = f2bf(ts[hr][d4 + 1]);
        o.z = f2bf(ts[hr][d4 + 2]); o.w = f2bf(ts[hr][d4 + 3]);
        *(us4*)(dst + (size_t)hr * D_N + d4) = o;
    }
}

// ---------------- grouped fused GEMM: 352x256 tile, BK=32, 4-buffer counted-vmcnt pipe --
// grid (32,8) = 256 blocks, 1/CU, ALL resident at t=0 (sum ceil(cnt/352) <= 31).
// Pipeline: 3 K-tiles staged ahead; raw s_barrier + counted vmcnt (loads stay in
// flight across barriers, T3/T4). Paired-row LDS swizzle keeps ds_read_b128 at
// 2 lanes/bank (free).
__global__ __launch_bounds__(512, 2) void gemm_kernel(
                            const u16* __restrict__ xbf,
                            const u16* __restrict__ w1t,
                            const float* __restrict__ b1,
                            const float* __restrict__ w2,
                            const u32* __restrict__ idxl,
                            const u32* __restrict__ counts,
                            float* __restrict__ llp) {
    extern __shared__ char lds[];
    // derive (k, mt) from counts — no desc array
    int k = -1, mt = 0, ntile = 0;
#pragma unroll
    for (int kk = 0; kk < K_N; ++kk) {
        int c = (int)counts[kk * 32];
        int t = (c + BM - 1) / BM;
        if ((int)blockIdx.x >= ntile && (int)blockIdx.x < ntile + t) { k = kk; mt = (int)blockIdx.x - ntile; }
        ntile += t;
    }
    if (k < 0) return;
    int cnt = (int)counts[k * 32];
    int nc = blockIdx.y;
    int rows = cnt - mt * BM; if (rows > BM) rows = BM;
    int tid = threadIdx.x;
    int lane = tid & 63, w = tid >> 6;
    int wm = w >> 2, wn = w & 3;
    int wmbase = wm * 176;
    int h0 = nc * BN;
    int l15 = lane & 15, l4 = lane >> 4;

    u32* ro = (u32*)(lds + RO_OFF);
    float* pll = (float*)(lds + PLL_OFF);

    if (tid < BM) {
        int m = mt * BM + tid;
        int mm = m < cnt ? m : cnt - 1;
        ro[tid] = idxl[(size_t)k * B_N + mm] * (u32)(D_N * 2);
    }
    __syncthreads();

    // staging source offsets, paired-row swizzled layout.
    // LDS chunk c (16B): row2=c>>3, s=c&7, u=s^(row2&7) -> row=2*row2+(u>>2), kchunk=u&3
    u32 srcA[3], srcB[2];
#pragma unroll
    for (int i = 0; i < 2; ++i) {
        int c = (i * 8 + w) * 64 + lane;
        int row2 = c >> 3, u = (c & 7) ^ (row2 & 7);
        srcA[i] = ro[row2 * 2 + (u >> 2)] + (u32)((u & 3) << 4);
    }
    if (w < 6) {
        int c = (16 + w) * 64 + lane;
        int row2 = c >> 3, u = (c & 7) ^ (row2 & 7);
        srcA[2] = ro[row2 * 2 + (u >> 2)] + (u32)((u & 3) << 4);
    } else {
        srcA[2] = 0;
    }
#pragma unroll
    for (int i = 0; i < 2; ++i) {
        int c = (i * 8 + w) * 64 + lane;
        int row2 = c >> 3, u = (c & 7) ^ (row2 & 7);
        srcB[i] = ((u32)(k * H_N + h0 + row2 * 2 + (u >> 2)) << 11) + (u32)((u & 3) << 4);
    }
    const char* xb = (const char*)xbf;
    const char* wb = (const char*)w1t;

    // per-lane fragment offset within a 16-row (8 pair-row) block:
    // slot = ((r&1)*4 + l4) ^ ((r>>1)&7); bases are all 0 mod 8 pair-rows.
    int sw = (((l15 & 1) << 2) | l4) ^ ((l15 >> 1) & 7);
    u32 foff = (u32)(((l15 >> 1) << 7) | (sw << 4));

    float4v acc[11][4];
#pragma unroll
    for (int mf = 0; mf < 11; ++mf)
#pragma unroll
        for (int nf = 0; nf < 4; ++nf)
            acc[mf][nf] = (float4v){0.f, 0.f, 0.f, 0.f};

    auto stage_tile = [&](int tt) {
        char* An = lds + (tt & 3) * BUFSZ;
        char* Bn = An + ABUF;
        u32 d = (u32)(tt << 6);
        async_copy16(An + w * 1024,           xb + srcA[0] + d);
        async_copy16(An + 8192 + w * 1024,    xb + srcA[1] + d);
        if (w < 6)
            async_copy16(An + 16384 + w * 1024, xb + srcA[2] + d);
        async_copy16(Bn + w * 1024,           wb + srcB[0] + d);
        async_copy16(Bn + 8192 + w * 1024,    wb + srcB[1] + d);
    };

    auto compute_tile = [&](int t) {
        const char* Acur = lds + (t & 3) * BUFSZ;
        const char* Af = Acur + wmbase * 64 + foff;
        const char* Bf = Acur + ABUF + (wn << 12) + foff;
        short8 bfv[4];
#pragma unroll
        for (int nf = 0; nf < 4; ++nf)
            bfv[nf] = *(const short8*)(Bf + nf * 1024);
        __builtin_amdgcn_s_setprio(1);
#pragma unroll
        for (int mf = 0; mf < 11; ++mf) {
            if ((wmbase + mf * 16) < rows) {
                short8 a = *(const short8*)(Af + mf * 1024);
#pragma unroll
                for (int nf = 0; nf < 4; ++nf)
                    acc[mf][nf] = __builtin_amdgcn_mfma_f32_16x16x32_bf16(a, bfv[nf], acc[mf][nf], 0, 0, 0);
            }
        }
        __builtin_amdgcn_s_setprio(0);
    };

    // waves 0-5 issue 5 vmem ops/tile, waves 6-7 issue 4 (A half-op only on w<6)
#define WAITV(NL, NH) do { \
        if (w < 6) asm volatile("s_waitcnt vmcnt(" #NL ") lgkmcnt(0)" ::: "memory"); \
        else       asm volatile("s_waitcnt vmcnt(" #NH ") lgkmcnt(0)" ::: "memory"); \
    } while (0)
#define BAR() do { __builtin_amdgcn_s_barrier(); asm volatile("" ::: "memory"); } while (0)

    // prologue: stage tiles 0..2 (3 tiles in flight)
    stage_tile(0); stage_tile(1); stage_tile(2);
    WAITV(10, 8);            // tile 0 landed; tiles 1,2 still in flight
    BAR();

    for (int t = 0; t < 29; ++t) {
        stage_tile(t + 3);   // into buffer freed at end of iter t-1
        compute_tile(t);
        WAITV(10, 8);        // tile t+1 landed; t+2, t+3 in flight
        BAR();
    }
    compute_tile(29);
    WAITV(5, 4);             // tile 30 landed; 31 in flight
    BAR();
    compute_tile(30);
    asm volatile("s_waitcnt vmcnt(0) lgkmcnt(0)" ::: "memory");
    BAR();
    compute_tile(31);

#undef WAITV
#undef BAR

    // epilogue: tanh + W2 weighted row-sum
    float w2v[4], b1v[4];
#pragma unroll
    for (int nf = 0; nf < 4; ++nf) {
        int h = h0 + wn * 64 + nf * 16 + l15;
        w2v[nf] = w2[k * H_N + h];
        b1v[nf] = b1[k * H_N + h];
    }
#pragma unroll
    for (int mf = 0; mf < 11; ++mf) {
        float rs[4] = {0.f, 0.f, 0.f, 0.f};
#pragma unroll
        for (int nf = 0; nf < 4; ++nf) {
#pragma unroll
            for (int r = 0; r < 4; ++r)
                rs[r] += fast_tanh(acc[mf][nf][r] + b1v[nf]) * w2v[nf];
        }
#pragma unroll
        for (int r = 0; r < 4; ++r) {
            float v = rs[r];
            v += __shfl_xor(v, 8);
            v += __shfl_xor(v, 4);
            v += __shfl_xor(v, 2);
            v += __shfl_xor(v, 1);
            if (l15 == 0) pll[wn * 352 + wmbase + mf * 16 + l4 * 4 + r] = v;
        }
    }
    __syncthreads();
    if (tid < BM) {
        int m = mt * BM + tid;
        if (m < cnt) {
            u32 b = idxl[(size_t)k * B_N + m];
            llp[(size_t)nc * B_N + b] = pll[tid] + pll[352 + tid] + pll[704 + tid] + pll[1056 + tid];
        }
    }
}

// ---------------- combine partials + b2 ----------------
__global__ void combine_kernel(const float* __restrict__ llp,
                               const int* __restrict__ cluster,
                               const float* __restrict__ b2,
                               float* __restrict__ out) {
    int b = blockIdx.x * 256 + threadIdx.x;
    float s = b2[cluster[b]];
#pragma unroll
    for (int nc = 0; nc < 8; ++nc) s += llp[(size_t)nc * B_N + b];
    out[b] = s;
}

extern "C" void kernel_launch(void* const* d_in, const int* in_sizes, int n_in,
                              void* d_out, int out_size, void* d_ws, size_t ws_size,
                              hipStream_t stream) {
    const float* x    = (const float*)d_in[0];
    const float* cent = (const float*)d_in[1];
    const float* W1   = (const float*)d_in[2];
    const float* b1   = (const float*)d_in[3];
    const float* W2   = (const float*)d_in[4];
    const float* b2   = (const float*)d_in[5];
    float* out = (float*)d_out;

    char* ws = (char*)d_ws;
    u16* xbf     = (u16*)(ws + 0);                 // 16 MB
    u16* w1t     = (u16*)(ws + 16777216);          // 32 MB
    u32* counts  = (u32*)(ws + 50331648);          // 8 strided u32 (1 KB pad)
    int* cluster = (int*)(ws + 50332672);          // 32 KB
    u32* idxl    = (u32*)(ws + 50365440);          // 256 KB
    float* llp   = (float*)(ws + 50627584);        // 256 KB

    (void)hipFuncSetAttribute((const void*)gemm_kernel,
                              hipFuncAttributeMaxDynamicSharedMemorySize, GEMM_LDS);

    hipLaunchKernelGGL(route_kernel, dim3(B_N / 4), dim3(256), 0, stream,
                       x, cent, xbf, cluster, counts);
    hipLaunchKernelGGL(scatter_kernel, dim3(32), dim3(256), 0, stream,
                       cluster, counts, idxl);
    hipLaunchKernelGGL(w1t_kernel, dim3(H_N / 64, D_N / 64, K_N), dim3(256), 0, stream,
                       W1, w1t);
    hipLaunchKernelGGL(gemm_kernel, dim3(GRID_MT, 8), dim3(512), GEMM_LDS, stream,
                       xbf, w1t, b1, W2, idxl, counts, llp);
    hipLaunchKernelGGL(combine_kernel, dim3(B_N / 256), dim3(256), 0, stream,
                       llp, cluster, b2, out);
}

// Round 2
// 87.064 us; speedup vs baseline: 1.0560x; 1.0560x over previous
//
#include <hip/hip_runtime.h>
#include <hip/hip_bf16.h>
#include <stdint.h>

#define B_N 8192
#define D_N 1024
#define K_N 8
#define H_N 2048

#define BM 320
#define BN 256
#define BK 64
#define GRID_MT 34
// LDS map (bytes): 2 K-step buffers of (A 40960 + B 32768) = 73728:
//   buf0=0 buf1=73728 (end 147456)
//   ro=147456(1280) pll=148736(5120)  total 153856 (<=163840)
#define ABYTES 40960
#define BUFSZ 73728
#define RO_OFF 147456
#define PLL_OFF 148736
#define GEMM_LDS 153856

typedef unsigned int u32;
typedef unsigned short u16;
typedef __attribute__((ext_vector_type(8))) short short8;
typedef __attribute__((ext_vector_type(4))) float float4v;

struct __align__(8) us4 { u16 x, y, z, w; };

__device__ __forceinline__ u16 f2bf(float f) {
    union { float f; u32 u; } v; v.f = f;
    u32 u = v.u;
    u32 r = (u + 0x7fffu + ((u >> 16) & 1u)) >> 16;
    return (u16)r;
}

__device__ __forceinline__ float fast_tanh(float x) {
    float t = __expf(2.0f * x);
    return 1.0f - 2.0f * __builtin_amdgcn_rcpf(t + 1.0f);
}

__device__ __forceinline__ void async_copy16(void* lds, const void* g) {
    __builtin_amdgcn_global_load_lds(
        (const __attribute__((address_space(1))) void*)g,
        (__attribute__((address_space(3))) void*)lds, 16, 0, 0);
}

// ---------------- routing: f64 argmin + x->bf16 (NO atomics) ----------------
__global__ void route_kernel(const float* __restrict__ x,
                             const float* __restrict__ cent,
                             u16* __restrict__ xbf,
                             int* __restrict__ cluster,
                             u32* __restrict__ counts) {
    int tid = threadIdx.x;
    if (blockIdx.x == 0 && tid < K_N) counts[tid * 32] = 0;  // zero strided counters
    int wave = tid >> 6, lane = tid & 63;
    int b = blockIdx.x * 4 + wave;
    const float* xr = x + (size_t)b * D_N;

    float4 xv[4];
#pragma unroll
    for (int i = 0; i < 4; ++i)
        xv[i] = *(const float4*)(xr + i * 256 + lane * 4);

#pragma unroll
    for (int i = 0; i < 4; ++i) {
        us4 o;
        o.x = f2bf(xv[i].x); o.y = f2bf(xv[i].y);
        o.z = f2bf(xv[i].z); o.w = f2bf(xv[i].w);
        *(us4*)(xbf + (size_t)b * D_N + i * 256 + lane * 4) = o;
    }

    double acc[K_N];
#pragma unroll
    for (int k = 0; k < K_N; ++k) {
        const float* cr = cent + k * D_N;
        double s = 0.0;
#pragma unroll
        for (int i = 0; i < 4; ++i) {
            float4 cv = *(const float4*)(cr + i * 256 + lane * 4);
            double d0 = (double)xv[i].x - (double)cv.x; s += d0 * d0;
            double d1 = (double)xv[i].y - (double)cv.y; s += d1 * d1;
            double d2 = (double)xv[i].z - (double)cv.z; s += d2 * d2;
            double d3 = (double)xv[i].w - (double)cv.w; s += d3 * d3;
        }
        acc[k] = s;
    }
#pragma unroll
    for (int k = 0; k < K_N; ++k) {
        double v = acc[k];
        for (int off = 32; off; off >>= 1) v += __shfl_down(v, off);
        acc[k] = v;
    }
    if (lane == 0) {
        int best = 0; double bv = acc[0];
#pragma unroll
        for (int k = 1; k < K_N; ++k)
            if (acc[k] < bv) { bv = acc[k]; best = k; }
        cluster[b] = best;
    }
}

// ---------------- parallel binning: 32 blocks, ballot-rank + block reserve ----------------
__global__ void scatter_kernel(const int* __restrict__ cluster,
                               u32* __restrict__ counts,
                               u32* __restrict__ idxl) {
    __shared__ u32 wcnt[4][K_N];
    __shared__ u32 gb[K_N];
    int tid = threadIdx.x;
    int b = blockIdx.x * 256 + tid;
    int lane = tid & 63, wid = tid >> 6;
    int cl = cluster[b];
    unsigned long long lower = (1ull << lane) - 1ull;
    u32 rank = 0;
#pragma unroll
    for (int k = 0; k < K_N; ++k) {
        unsigned long long mk = __ballot(cl == k);
        if (k == cl) rank = (u32)__popcll(mk & lower);
        if (lane == 0) wcnt[wid][k] = (u32)__popcll(mk);
    }
    __syncthreads();
    if (tid < K_N) {
        u32 tot = wcnt[0][tid] + wcnt[1][tid] + wcnt[2][tid] + wcnt[3][tid];
        gb[tid] = atomicAdd(&counts[tid * 32], tot);   // reserve range (order-free)
    }
    __syncthreads();
    u32 woff = 0;
    if (wid > 0) woff += wcnt[0][cl];
    if (wid > 1) woff += wcnt[1][cl];
    if (wid > 2) woff += wcnt[2][cl];
    idxl[(size_t)cl * B_N + gb[cl] + woff + rank] = (u32)b;
}

// ---------------- W1[k,d,h] f32 -> W1t[k,h,d] bf16 (vectorized) ----------------
__global__ void w1t_kernel(const float* __restrict__ w1, u16* __restrict__ w1t) {
    __shared__ float ts[64][65];
    int tid = threadIdx.x;
    int h0 = blockIdx.x * 64, d0 = blockIdx.y * 64, k = blockIdx.z;
    const float* src = w1 + ((size_t)k * D_N + d0) * H_N + h0;
#pragma unroll
    for (int i = 0; i < 4; ++i) {
        int q = i * 256 + tid;
        int r = q >> 4, c4 = (q & 15) * 4;          // d-row, h-col4
        float4 v = *(const float4*)(src + (size_t)r * H_N + c4);
        ts[c4 + 0][r] = v.x; ts[c4 + 1][r] = v.y;
        ts[c4 + 2][r] = v.z; ts[c4 + 3][r] = v.w;
    }
    __syncthreads();
    u16* dst = w1t + ((size_t)k * H_N + h0) * D_N + d0;
#pragma unroll
    for (int i = 0; i < 4; ++i) {
        int q = i * 256 + tid;
        int hr = q >> 4, d4 = (q & 15) * 4;         // h-row, d-col4
        us4 o;
        o.x = f2bf(ts[hr][d4 + 0]); o.y = f2bf(ts[hr][d4 + 1]);
        o.z = f2bf(ts[hr][d4 + 2]); o.w = f2bf(ts[hr][d4 + 3]);
        *(us4*)(dst + (size_t)hr * D_N + d4) = o;
    }
}

// ---------------- grouped fused GEMM: 320x256 tile, BK=64, 4-phase interleaved schedule --
// BM=320 -> ceil(1024±30 / 320)=4 M-tiles/expert -> 32x8 = 256 blocks = 1/CU, all CUs.
// Per K-step (BK=64): 4 phases {ds_reads | stage issue | bar | lgkm0 | 20 MFMA | bar},
// split (kk, mf-half); B frags register-cached per kk -> each LDS frag read once/step.
// One vmcnt(0) per step at P0 (drains exactly the 9 stage ops issued a full step ago).
__global__ __launch_bounds__(512, 2) void gemm_kernel(
                            const u16* __restrict__ xbf,
                            const u16* __restrict__ w1t,
                            const float* __restrict__ b1,
                            const float* __restrict__ w2,
                            const u32* __restrict__ idxl,
                            const u32* __restrict__ counts,
                            float* __restrict__ llp) {
    extern __shared__ char lds[];
    // derive (k, mt) from counts — no desc array
    int k = -1, mt = 0, ntile = 0;
#pragma unroll
    for (int kk = 0; kk < K_N; ++kk) {
        int c = (int)counts[kk * 32];
        int t = (c + BM - 1) / BM;
        if ((int)blockIdx.x >= ntile && (int)blockIdx.x < ntile + t) { k = kk; mt = (int)blockIdx.x - ntile; }
        ntile += t;
    }
    if (k < 0) return;
    int cnt = (int)counts[k * 32];
    int nc = blockIdx.y;
    int rows = cnt - mt * BM; if (rows > BM) rows = BM;
    int tid = threadIdx.x;
    int lane = tid & 63, w = tid >> 6;
    int wm = w >> 2, wn = w & 3;
    int wmbase = wm * 160;
    int h0 = nc * BN;
    int l15 = lane & 15, l4 = lane >> 4;

    u32* ro = (u32*)(lds + RO_OFF);
    float* pll = (float*)(lds + PLL_OFF);

    if (tid < BM) {
        int m = mt * BM + tid;
        int mm = m < cnt ? m : cnt - 1;
        ro[tid] = idxl[(size_t)k * B_N + mm] * (u32)(D_N * 2);
    }
    __syncthreads();

    // staging source offsets (pre-swizzled: linear LDS dest + swizzled read)
    u32 srcA[5], srcB[4];
#pragma unroll
    for (int i = 0; i < 5; ++i) {
        int c = i * 512 + tid; int r = c >> 3, j = c & 7;
        srcA[i] = ro[r] + ((u32)(j ^ (r & 7)) << 4);
    }
#pragma unroll
    for (int i = 0; i < 4; ++i) {
        int c = i * 512 + tid; int r = c >> 3, j = c & 7;
        srcB[i] = ((u32)(k * H_N + h0 + r) << 11) + ((u32)(j ^ (r & 7)) << 4);
    }
    const char* xb = (const char*)xbf;
    const char* wb = (const char*)w1t;

    // per-lane fragment base offsets (chunk = (kk*4+l4) ^ (row&7); row&7 == l15&7)
    int swz = l15 & 7;
    u32 aB0 = (u32)((wmbase + l15) * 128 + (((0 + l4) ^ swz) << 4));
    u32 aB1 = (u32)((wmbase + l15) * 128 + (((4 + l4) ^ swz) << 4));
    u32 bB0 = (u32)(ABYTES + (wn * 64 + l15) * 128 + (((0 + l4) ^ swz) << 4));
    u32 bB1 = (u32)(ABYTES + (wn * 64 + l15) * 128 + (((4 + l4) ^ swz) << 4));

    float4v acc[10][4];
#pragma unroll
    for (int mf = 0; mf < 10; ++mf)
#pragma unroll
        for (int nf = 0; nf < 4; ++nf)
            acc[mf][nf] = (float4v){0.f, 0.f, 0.f, 0.f};

#define STA(BUF, I, D) async_copy16((BUF) + (I) * 8192 + w * 1024, xb + srcA[I] + (D))
#define STB(BUF, I, D) async_copy16((BUF) + ABYTES + (I) * 8192 + w * 1024, wb + srcB[I] + (D))
#define BAR() do { asm volatile("" ::: "memory"); __builtin_amdgcn_s_barrier(); \
                   asm volatile("" ::: "memory"); } while (0)
#define LGKM0_PIN() do { asm volatile("s_waitcnt lgkmcnt(0)" ::: "memory"); \
                         __builtin_amdgcn_sched_barrier(0); } while (0)
#define MFMA_PHASE(MFB, BREG)                                                    \
    do {                                                                         \
        __builtin_amdgcn_s_setprio(1);                                           \
        _Pragma("unroll")                                                        \
        for (int i_ = 0; i_ < 5; ++i_) {                                         \
            if (wmbase + ((MFB) + i_) * 16 < rows) {                             \
                _Pragma("unroll")                                                \
                for (int nf_ = 0; nf_ < 4; ++nf_)                                \
                    acc[(MFB) + i_][nf_] = __builtin_amdgcn_mfma_f32_16x16x32_bf16( \
                        a[i_], BREG[nf_], acc[(MFB) + i_][nf_], 0, 0, 0);        \
            }                                                                    \
        }                                                                        \
        __builtin_amdgcn_s_setprio(0);                                           \
    } while (0)

    // prologue: stage K-step 0 into buf 0 (drained by P0's vmcnt at t=0)
    {
        char* Bp = lds;
        STA(Bp, 0, 0); STA(Bp, 1, 0); STA(Bp, 2, 0); STA(Bp, 3, 0); STA(Bp, 4, 0);
        STB(Bp, 0, 0); STB(Bp, 1, 0); STB(Bp, 2, 0); STB(Bp, 3, 0);
    }

    for (int t = 0; t < 16; ++t) {
        const char* Acur = lds + (t & 1) * BUFSZ;
        char* Bnx = lds + ((t + 1) & 1) * BUFSZ;
        u32 d = (u32)((t + 1) << 7);
        bool pre = (t < 15);
        short8 a[5], bC[4];

        // ---- P0: buffer-t ready gate; read B(kk0)+A(kk0, mf0-4); stage B0-B2
        asm volatile("s_waitcnt vmcnt(0)" ::: "memory");
        BAR();
#pragma unroll
        for (int nf = 0; nf < 4; ++nf)
            bC[nf] = *(const short8*)(Acur + bB0 + nf * 2048);
#pragma unroll
        for (int i = 0; i < 5; ++i)
            a[i] = *(const short8*)(Acur + aB0 + i * 2048);
        if (pre) { STB(Bnx, 0, d); STB(Bnx, 1, d); STB(Bnx, 2, d); }
        BAR();
        LGKM0_PIN();
        MFMA_PHASE(0, bC);

        // ---- P1: read A(kk0, mf5-9); stage B3,A0,A1
        BAR();
#pragma unroll
        for (int i = 0; i < 5; ++i)
            a[i] = *(const short8*)(Acur + aB0 + (5 + i) * 2048);
        if (pre) { STB(Bnx, 3, d); STA(Bnx, 0, d); STA(Bnx, 1, d); }
        BAR();
        LGKM0_PIN();
        MFMA_PHASE(5, bC);

        // ---- P2: read B(kk1)+A(kk1, mf0-4); stage A2,A3,A4
        BAR();
#pragma unroll
        for (int nf = 0; nf < 4; ++nf)
            bC[nf] = *(const short8*)(Acur + bB1 + nf * 2048);
#pragma unroll
        for (int i = 0; i < 5; ++i)
            a[i] = *(const short8*)(Acur + aB1 + i * 2048);
        if (pre) { STA(Bnx, 2, d); STA(Bnx, 3, d); STA(Bnx, 4, d); }
        BAR();
        LGKM0_PIN();
        MFMA_PHASE(0, bC);

        // ---- P3: read A(kk1, mf5-9); no staging
        BAR();
#pragma unroll
        for (int i = 0; i < 5; ++i)
            a[i] = *(const short8*)(Acur + aB1 + (5 + i) * 2048);
        BAR();
        LGKM0_PIN();
        MFMA_PHASE(5, bC);
    }

#undef STA
#undef STB
#undef BAR
#undef LGKM0_PIN
#undef MFMA_PHASE

    // epilogue: tanh + W2 weighted row-sum
    float w2v[4], b1v[4];
#pragma unroll
    for (int nf = 0; nf < 4; ++nf) {
        int h = h0 + wn * 64 + nf * 16 + l15;
        w2v[nf] = w2[k * H_N + h];
        b1v[nf] = b1[k * H_N + h];
    }
#pragma unroll
    for (int mf = 0; mf < 10; ++mf) {
        float rs[4] = {0.f, 0.f, 0.f, 0.f};
#pragma unroll
        for (int nf = 0; nf < 4; ++nf) {
#pragma unroll
            for (int r = 0; r < 4; ++r)
                rs[r] += fast_tanh(acc[mf][nf][r] + b1v[nf]) * w2v[nf];
        }
#pragma unroll
        for (int r = 0; r < 4; ++r) {
            float v = rs[r];
            v += __shfl_xor(v, 8);
            v += __shfl_xor(v, 4);
            v += __shfl_xor(v, 2);
            v += __shfl_xor(v, 1);
            if (l15 == 0) pll[wn * 320 + wmbase + mf * 16 + l4 * 4 + r] = v;
        }
    }
    __syncthreads();
    if (tid < BM) {
        int m = mt * BM + tid;
        if (m < cnt) {
            u32 b = idxl[(size_t)k * B_N + m];
            llp[(size_t)nc * B_N + b] = pll[tid] + pll[320 + tid] + pll[640 + tid] + pll[960 + tid];
        }
    }
}

// ---------------- combine partials + b2 ----------------
__global__ void combine_kernel(const float* __restrict__ llp,
                               const int* __restrict__ cluster,
                               const float* __restrict__ b2,
                               float* __restrict__ out) {
    int b = blockIdx.x * 256 + threadIdx.x;
    float s = b2[cluster[b]];
#pragma unroll
    for (int nc = 0; nc < 8; ++nc) s += llp[(size_t)nc * B_N + b];
    out[b] = s;
}

extern "C" void kernel_launch(void* const* d_in, const int* in_sizes, int n_in,
                              void* d_out, int out_size, void* d_ws, size_t ws_size,
                              hipStream_t stream) {
    const float* x    = (const float*)d_in[0];
    const float* cent = (const float*)d_in[1];
    const float* W1   = (const float*)d_in[2];
    const float* b1   = (const float*)d_in[3];
    const float* W2   = (const float*)d_in[4];
    const float* b2   = (const float*)d_in[5];
    float* out = (float*)d_out;

    char* ws = (char*)d_ws;
    u16* xbf     = (u16*)(ws + 0);                 // 16 MB
    u16* w1t     = (u16*)(ws + 16777216);          // 32 MB
    u32* counts  = (u32*)(ws + 50331648);          // 8 strided u32 (1 KB pad)
    int* cluster = (int*)(ws + 50332672);          // 32 KB
    u32* idxl    = (u32*)(ws + 50365440);          // 256 KB
    float* llp   = (float*)(ws + 50627584);        // 256 KB

    (void)hipFuncSetAttribute((const void*)gemm_kernel,
                              hipFuncAttributeMaxDynamicSharedMemorySize, GEMM_LDS);

    hipLaunchKernelGGL(route_kernel, dim3(B_N / 4), dim3(256), 0, stream,
                       x, cent, xbf, cluster, counts);
    hipLaunchKernelGGL(scatter_kernel, dim3(32), dim3(256), 0, stream,
                       cluster, counts, idxl);
    hipLaunchKernelGGL(w1t_kernel, dim3(H_N / 64, D_N / 64, K_N), dim3(256), 0, stream,
                       W1, w1t);
    hipLaunchKernelGGL(gemm_kernel, dim3(GRID_MT, 8), dim3(512), GEMM_LDS, stream,
                       xbf, w1t, b1, W2, idxl, counts, llp);
    hipLaunchKernelGGL(combine_kernel, dim3(B_N / 256), dim3(256), 0, stream,
                       llp, cluster, b2, out);
}